// Round 10
// baseline (208.157 us; speedup 1.0000x reference)
//
#include <hip/hip_runtime.h>
#include <hip/hip_bf16.h>
#include <type_traits>

typedef __attribute__((ext_vector_type(8))) _Float16 half8;
typedef __attribute__((ext_vector_type(4))) _Float16 half4;
typedef __attribute__((ext_vector_type(2))) _Float16 half2;
typedef __attribute__((ext_vector_type(4))) float f32x4;

constexpr int CB = 48, CS = 128, CW = 4, CK = 256;
constexpr int LDP = 264;  // padded ebuf row stride (halves)

// eT[b][k][kp] = exp(T[b][k][kp] * tag_mask[b][k][kp]) as f16, float4-vectorized
__global__ void prep_eT_kernel(const f32x4* __restrict__ T,
                               const f32x4* __restrict__ tm,
                               half4* __restrict__ eT, int n4) {
    int i = blockIdx.x * 256 + threadIdx.x;
    if (i < n4) {
        f32x4 t = T[i], m = tm[i];
        half4 o;
        o[0] = (_Float16)__expf(t[0] * m[0]);
        o[1] = (_Float16)__expf(t[1] * m[1]);
        o[2] = (_Float16)__expf(t[2] * m[2]);
        o[3] = (_Float16)__expf(t[3] * m[3]);
        eT[i] = o;
    }
}

// 4 waves / 256 threads. Round-10: Y-MEMOIZATION. Between steps only ONE ring row
// changes, so y[r][k] for the other 3 slots is recomputed identically by the MFMA
// tile (which also wastes 12/16 M-rows). Instead: thread owns k=tid, keeps Y[4]
// in registers, and recomputes only Y[sp] per step as a 256-MAC dot (128 fdot2,
// 8 chains) of the broadcast-read e-row against its register-resident eT row.
// sum_prev via an 8-MFMA ones-chain on the idle matrix pipe (no shfl chains —
// rounds 7-9 showed head-side cross-lane/trail work is poison). Prefetch, E/trail
// placement, and barrier are byte-identical to round 5 (the measured best).
__global__ __launch_bounds__(256, 1)
void crf_scan_kernel(const float* __restrict__ logits,
                     const float* __restrict__ ham,
                     const _Float16* __restrict__ eT,
                     const float* __restrict__ tag_mask,
                     const int* __restrict__ text_mask,
                     float* __restrict__ out) {
    const int b = blockIdx.x;
    const int tid = (int)threadIdx.x;
    const int wv = tid >> 6;
    const int lane = tid & 63;
    const int g4 = lane >> 4;

    __shared__ alignas(16) _Float16 ebuf[4 * LDP];  // ring: slot of alpha_i = i&3
    __shared__ float red[4];
    __shared__ int len_s;

    if (tid == 0) len_s = 0;
    __syncthreads();
    if (tid < CS) atomicAdd(&len_s, text_mask[b * CS + tid]);
    // alpha_{-1} = zeros row: e = exp(0-0) = 1 in slot 3, M_{-1} = 0
    ebuf[3 * LDP + tid] = (_Float16)1.0f;

    const float tm0 = tag_mask[(size_t)b * CK * CK + tid];  // tag_mask[b,0,k]

    // per-thread eT row: et[i] = eT[b][tid][8i..8i+8)  (64 VGPRs, register-resident)
    half8 et[32];
    {
        const _Float16* eTr = eT + (size_t)b * CK * CK + (size_t)tid * CK;
#pragma unroll
        for (int i = 0; i < 32; ++i) et[i] = *(const half8*)(eTr + 8 * i);
    }

    const float* lgb = logits + (size_t)b * CS * CW * CK;
    const float* hcb = ham    + (size_t)b * CS * CW * CK;

    // Y memo: Y[r] = y for slot r at this thread's k. Entries are consumed only
    // after being computed (first-block masks cover the rest) -> init value moot.
    float Y[4] = {0.0f, 0.0f, 0.0f, 0.0f};

    // wave-uniform scan state
    float mr[4] = {0.0f, 0.0f, 0.0f, 0.0f};  // mr[s] = normalizer M of alpha in slot s
    float ls_prev = __logf(256.0f) - 2.0f;   // pretend ls_{-1}
    float out_r = __logf(256.0f);            // ls[0] (len==0 case)
    float e_last = 0.0f, M_last = 0.0f;
    // deferred normalizer: Mcur/scl for step j are decided at step j-1 (round-5 scheme).
    float Mcur = __logf(256.0f) + 2.0f;      // M_0 = log256 + 2
    float scl  = __expf(0.0f - Mcur);        // C_0 = mr[3] = 0

    // 4-deep emission prefetch: set s holds step with j&3==s
    float lgp[4][4], hcp[4][4];
#pragma unroll
    for (int s = 0; s < 4; ++s)
#pragma unroll
        for (int w = 0; w < 4; ++w) {
            int idx = s * (CW * CK) + w * CK + tid;
            lgp[s][w] = lgb[idx];
            hcp[s][w] = hcb[idx];
        }

    __syncthreads();
    const int len = len_s;

    half8 ones;
#pragma unroll
    for (int i = 0; i < 8; ++i) ones[i] = (_Float16)1.0f;

    auto step = [&](int j, auto uc, auto firstc) {
        constexpr int u = uc.value;          // j & 3 (slot written this step)
        constexpr bool first = firstc.value; // j < 4 block
        constexpr int sp = (u + 3) & 3;      // slot of alpha_{j-1}

        const _Float16* rowp = ebuf + sp * LDP;

        // broadcast-read the fresh e-row (all lanes same address: conflict-free
        // broadcast) + 8 g4-addressed fragments for the sum-MFMA
        half8 er[32];
#pragma unroll
        for (int i = 0; i < 32; ++i) er[i] = *(const half8*)(rowp + 8 * i);
        half8 saf[8];
#pragma unroll
        for (int c = 0; c < 8; ++c) saf[c] = *(const half8*)(rowp + c * 32 + g4 * 8);

        // sum_prev = rowsum of e-row via ones-MFMA chain (idle matrix pipe, no
        // cross-lane ops; D is wave-uniform). Consumed only by the tail trail.
        f32x4 sacc = (f32x4){0.0f, 0.0f, 0.0f, 0.0f};
#pragma unroll
        for (int c = 0; c < 8; ++c)
            sacc = __builtin_amdgcn_mfma_f32_16x16x32_f16(saf[c], ones, sacc, 0, 0, 0);

        // consume prefetch set u (issued 4 steps ago)
        float em_w[4];
#pragma unroll
        for (int w = 0; w < 4; ++w)
            em_w[w] = (lgp[u][w] + hcp[u][w]) * tm0;

        // reissue set u for step j+4 (stays in flight across raw barriers)
        {
            int jn = (j + 4 < CS) ? j + 4 : 0;  // wave-uniform clamp (dummy ok)
#pragma unroll
            for (int w = 0; w < 4; ++w) {
                int idx = jn * (CW * CK) + w * CK + tid;
                lgp[u][w] = lgb[idx];
                hcp[u][w] = hcb[idx];
            }
        }

        // slot weights from OLD mr (read before mr[u] update)
        const float C = mr[sp];
        float E[4];
#pragma unroll
        for (int r = 0; r < 4; ++r)
            E[r] = __expf(mr[r] + em_w[(u + 3 - r) & 3] - C);
        mr[u] = Mcur;   // record M_j (after E read old mr[u])

        // Y[sp] = e-row . et-row : 128 fdot2 in 8 parallel chains
        float a0 = 0, a1 = 0, a2 = 0, a3 = 0, a4 = 0, a5 = 0, a6 = 0, a7 = 0;
#pragma unroll
        for (int i = 0; i < 32; ++i) {
#pragma unroll
            for (int q = 0; q < 4; ++q) {
                half2 ep = {er[i][2 * q], er[i][2 * q + 1]};
                half2 tp = {et[i][2 * q], et[i][2 * q + 1]};
                const int c = (i * 4 + q) & 7;
                if (c == 0) a0 = __builtin_amdgcn_fdot2(ep, tp, a0, false);
                else if (c == 1) a1 = __builtin_amdgcn_fdot2(ep, tp, a1, false);
                else if (c == 2) a2 = __builtin_amdgcn_fdot2(ep, tp, a2, false);
                else if (c == 3) a3 = __builtin_amdgcn_fdot2(ep, tp, a3, false);
                else if (c == 4) a4 = __builtin_amdgcn_fdot2(ep, tp, a4, false);
                else if (c == 5) a5 = __builtin_amdgcn_fdot2(ep, tp, a5, false);
                else if (c == 6) a6 = __builtin_amdgcn_fdot2(ep, tp, a6, false);
                else a7 = __builtin_amdgcn_fdot2(ep, tp, a7, false);
            }
        }
        Y[sp] = ((a0 + a4) + (a1 + a5)) + ((a2 + a6) + (a3 + a7));

        // per-thread epilogue: thread owns k=tid, no tile selection needed
        float S = 0.0f;
#pragma unroll
        for (int r = 0; r < 4; ++r) {
            float yv = Y[r];
            if (first) {
                const int w = (u + 3 - r) & 3;   // width feeding slot r this step
                if (w == j) yv = 256.0f;         // initial-state path (alpha_{-1}=0 over K)
                else if (w > j) yv = 0.0f;       // invalid span
            }
            S = fmaf(yv, E[r], S);
        }
        float e = S * scl;                       // scl precomputed last step
        ebuf[u * LDP + tid] = (_Float16)e;
        e_last = e;
        M_last = Mcur;

        // trail (round-5 placement: tail): ls_j, output select, next normalizer.
        // sacc has been ready since mid-step (8-MFMA chain on idle pipe).
        float sum_prev = sacc[0];                // wave-uniform rowsum of slot sp
        float lsj = C + __logf(sum_prev);        // ls[j] = LSE(alpha_{j-1})
        if (j == len) out_r = lsj;
        float delta = lsj - ls_prev;
        ls_prev = lsj;
        float Mn = lsj + 2.0f * delta;           // predict ls_{j+1} + delta_{j+1}
        scl = __expf(Mcur - Mn);                 // C_{j+1} = M_j = Mcur
        Mcur = Mn;

        // LDS visibility only; emission prefetch stays in flight (no vmcnt drain)
        asm volatile("s_waitcnt lgkmcnt(0)" ::: "memory");
        __builtin_amdgcn_s_barrier();
        __builtin_amdgcn_sched_barrier(0);
    };

#define IC(v) std::integral_constant<int, v>{}
#define BC(v) std::integral_constant<bool, v>{}
    step(0, IC(0), BC(true));
    step(1, IC(1), BC(true));
    step(2, IC(2), BC(true));
    step(3, IC(3), BC(true));
    for (int jj = 4; jj < CS; jj += 4) {
        step(jj + 0, IC(0), BC(false));
        step(jj + 1, IC(1), BC(false));
        step(jj + 2, IC(2), BC(false));
        step(jj + 3, IC(3), BC(false));
    }
#undef IC
#undef BC

    // ls[128] = M_127 + log(sum_k e_127)
    float s = e_last;
#pragma unroll
    for (int o = 32; o; o >>= 1) s += __shfl_xor(s, o, 64);
    if (lane == 0) red[wv] = s;
    __syncthreads();
    if (tid == 0) {
        float tot = red[0] + red[1] + red[2] + red[3];
        float ls_full = M_last + __logf(tot);
        if (len == CS) out_r = ls_full;
        out[b] = out_r;
    }
}

extern "C" void kernel_launch(void* const* d_in, const int* in_sizes, int n_in,
                              void* d_out, int out_size, void* d_ws, size_t ws_size,
                              hipStream_t stream) {
    const float* logits    = (const float*)d_in[0];
    const float* T         = (const float*)d_in[1];
    const float* ham       = (const float*)d_in[2];
    const float* tag_mask  = (const float*)d_in[3];
    const int*   text_mask = (const int*)d_in[4];
    float* out = (float*)d_out;

    _Float16* eT = (_Float16*)d_ws;  // CB*CK*CK f16 = 6.3 MB scratch
    int n4 = CB * CK * CK / 4;
    prep_eT_kernel<<<(n4 + 255) / 256, 256, 0, stream>>>(
        (const f32x4*)T, (const f32x4*)tag_mask, (half4*)eT, n4);
    crf_scan_kernel<<<CB, 256, 0, stream>>>(logits, ham, eT, tag_mask, text_mask, out);
}

// Round 11
// 183.093 us; speedup vs baseline: 1.1369x; 1.1369x over previous
//
#include <hip/hip_runtime.h>
#include <hip/hip_bf16.h>
#include <type_traits>

typedef __attribute__((ext_vector_type(8))) _Float16 half8;
typedef __attribute__((ext_vector_type(4))) float f32x4;

constexpr int CB = 48, CS = 128, CW = 4, CK = 256;
constexpr int LDP = 264;  // padded ebuf row stride (halves)

// 4 waves / 256 threads (measured-best round-5 structure; 1 wave/SIMD = full register
// budget). Round-11: prep_eT kernel FUSED into init — each block computes its own
// exp(T*mask) fragments directly (bit-exact same f32 ops), deleting the separate
// dispatch and the 6.3MB eT write + read round-trip. Scan step body is byte-identical
// to round 5 (84.4 us measured).
__global__ __launch_bounds__(256, 1)
void crf_scan_kernel(const float* __restrict__ logits,
                     const float* __restrict__ Tmat,
                     const float* __restrict__ ham,
                     const float* __restrict__ tag_mask,
                     const int* __restrict__ text_mask,
                     float* __restrict__ out) {
    const int b = blockIdx.x;
    const int tid = (int)threadIdx.x;
    const int wv = tid >> 6;
    const int lane = tid & 63;
    const int l16 = lane & 15;
    const int g4 = lane >> 4;

    __shared__ alignas(16) _Float16 ebuf[4 * LDP];  // ring: slot of alpha_i = i&3
    __shared__ float red[4];
    __shared__ int len_s;

    if (tid == 0) len_s = 0;
    __syncthreads();
    if (tid < CS) atomicAdd(&len_s, text_mask[b * CS + tid]);
    // alpha_{-1} = zeros row: e = exp(0-0) = 1 in slot 3, M_{-1} = 0
    ebuf[3 * LDP + tid] = (_Float16)1.0f;

    const float tm0 = tag_mask[(size_t)b * CK * CK + tid];  // tag_mask[b,0,k]

    // persistent eT B-fragments, computed in-place from T*tag_mask (fused prep):
    // bfr[c][t][i] = (f16) expf(T[b][k][kp] * mask[b][k][kp]),
    // k = wv*64 + t*16 + l16, kp = c*32 + g4*8 + i  — identical values to the old
    // prep_eT kernel (same f32 ops, same cast). One-time cost ~256 exps/thread.
    half8 bfr[8][4];
    {
        const float* Tb  = Tmat     + (size_t)b * CK * CK;
        const float* tmb = tag_mask + (size_t)b * CK * CK;
#pragma unroll
        for (int c = 0; c < 8; ++c)
#pragma unroll
            for (int t = 0; t < 4; ++t) {
                int k = wv * 64 + t * 16 + l16;
                size_t off = (size_t)k * CK + c * 32 + g4 * 8;
                const f32x4* tp = (const f32x4*)(Tb + off);
                const f32x4* mp = (const f32x4*)(tmb + off);
                f32x4 t0 = tp[0], t1 = tp[1];
                f32x4 m0 = mp[0], m1 = mp[1];
                half8 o;
                o[0] = (_Float16)__expf(t0[0] * m0[0]);
                o[1] = (_Float16)__expf(t0[1] * m0[1]);
                o[2] = (_Float16)__expf(t0[2] * m0[2]);
                o[3] = (_Float16)__expf(t0[3] * m0[3]);
                o[4] = (_Float16)__expf(t1[0] * m1[0]);
                o[5] = (_Float16)__expf(t1[1] * m1[1]);
                o[6] = (_Float16)__expf(t1[2] * m1[2]);
                o[7] = (_Float16)__expf(t1[3] * m1[3]);
                bfr[c][t] = o;
            }
    }

    const float* lgb = logits + (size_t)b * CS * CW * CK;
    const float* hcb = ham    + (size_t)b * CS * CW * CK;

    // persistent A-fragments, slot-duplicated rows: A row r holds slot (r&3).
    half8 af[8];
    {
        const _Float16 iv = ((l16 & 3) == 3) ? (_Float16)1.0f : (_Float16)0.0f;
        half8 v;
#pragma unroll
        for (int i = 0; i < 8; ++i) v[i] = iv;
#pragma unroll
        for (int c = 0; c < 8; ++c) af[c] = v;
    }

    // wave-uniform scan state
    float mr[4] = {0.0f, 0.0f, 0.0f, 0.0f};  // mr[s] = normalizer M of alpha in slot s
    float ls_prev = __logf(256.0f) - 2.0f;   // pretend ls_{-1}
    float out_r = __logf(256.0f);            // ls[0] (len==0 case)
    float e_last = 0.0f, M_last = 0.0f;
    // deferred normalizer: Mcur/scl for step j are decided at step j-1.
    float Mcur = __logf(256.0f) + 2.0f;      // M_0 = log256 + 2
    float scl  = __expf(0.0f - Mcur);        // C_0 = mr[3] = 0

    // 4-deep emission prefetch: set s holds step with j&3==s
    float lgp[4][4], hcp[4][4];
#pragma unroll
    for (int s = 0; s < 4; ++s)
#pragma unroll
        for (int w = 0; w < 4; ++w) {
            int idx = s * (CW * CK) + w * CK + tid;
            lgp[s][w] = lgb[idx];
            hcp[s][w] = hcb[idx];
        }

    __syncthreads();
    const int len = len_s;

    half8 ones;
#pragma unroll
    for (int i = 0; i < 8; ++i) ones[i] = (_Float16)1.0f;

    auto step = [&](int j, auto uc, auto firstc) {
        constexpr int u = uc.value;          // j & 3 (slot written this step)
        constexpr bool first = firstc.value; // j < 4 block
        constexpr int sp = (u + 3) & 3;      // slot of alpha_{j-1}

        // masked A-frag update: only row group sp changed since last step (16/64 lanes,
        // broadcast addresses within each group -> conflict-free)
        if ((l16 & 3) == sp) {
#pragma unroll
            for (int c = 0; c < 8; ++c)
                af[c] = *(const half8*)(ebuf + sp * LDP + c * 32 + g4 * 8);
        }

        // consume prefetch set u (issued 4 steps ago)
        float em_w[4];
#pragma unroll
        for (int w = 0; w < 4; ++w)
            em_w[w] = (lgp[u][w] + hcp[u][w]) * tm0;

        // reissue set u for step j+4 (stays in flight across raw barriers)
        {
            int jn = (j + 4 < CS) ? j + 4 : 0;  // wave-uniform clamp (dummy ok)
#pragma unroll
            for (int w = 0; w < 4; ++w) {
                int idx = jn * (CW * CK) + w * CK + tid;
                lgp[u][w] = lgb[idx];
                hcp[u][w] = hcb[idx];
            }
        }

        // slot weights need only mr[]/C (known since last step) -> off the MFMA path
        const float C = mr[sp];
        float E[4];
#pragma unroll
        for (int r = 0; r < 4; ++r)
            E[r] = __expf(mr[r] + em_w[(u + 3 - r) & 3] - C);
        mr[u] = Mcur;   // record this step's normalizer (after E read old mr[u])

        // MFMA: y[slot r][k] for 4 k-tiles + all-ones tile for row sums
        f32x4 acc[4];
#pragma unroll
        for (int t = 0; t < 4; ++t) acc[t] = (f32x4){0.0f, 0.0f, 0.0f, 0.0f};
        f32x4 s0 = {0, 0, 0, 0}, s1 = {0, 0, 0, 0};
#pragma unroll
        for (int c = 0; c < 8; ++c) {
#pragma unroll
            for (int t = 0; t < 4; ++t)
                acc[t] = __builtin_amdgcn_mfma_f32_16x16x32_f16(af[c], bfr[c][t], acc[t], 0, 0, 0);
            if (c & 1) s1 = __builtin_amdgcn_mfma_f32_16x16x32_f16(af[c], ones, s1, 0, 0, 0);
            else       s0 = __builtin_amdgcn_mfma_f32_16x16x32_f16(af[c], ones, s0, 0, 0, 0);
        }
        f32x4 rsum = s0 + s1;   // rsum[r] = rowsum of slot r (wave-uniform)

        // transpose-free epilogue: lane's k = tid lives in tile t = g4, reg r = slot r
        float S = 0.0f;
#pragma unroll
        for (int r = 0; r < 4; ++r) {
            float v01 = (g4 & 1) ? acc[1][r] : acc[0][r];
            float v23 = (g4 & 1) ? acc[3][r] : acc[2][r];
            float yv  = (g4 & 2) ? v23 : v01;
            if (first) {
                const int w = (u + 3 - r) & 3;   // width feeding slot r this step
                if (w == j) yv = 256.0f;         // initial-state path (alpha_{-1}=0 over K)
                else if (w > j) yv = 0.0f;       // invalid span
            }
            S = fmaf(yv, E[r], S);
        }
        float e = S * scl;                       // scl precomputed last step
        ebuf[u * LDP + tid] = (_Float16)e;
        e_last = e;
        M_last = Mcur;

        // trail (off the store path): ls_j, output select, next normalizer
        float lsj = C + __logf(rsum[sp]);        // ls[j] = LSE(alpha_{j-1})
        if (j == len) out_r = lsj;
        float delta = lsj - ls_prev;
        ls_prev = lsj;
        float Mn = lsj + 2.0f * delta;           // predict ls_{j+1} + delta_{j+1}
        scl = __expf(Mcur - Mn);                 // C_{j+1} = M_j = Mcur
        Mcur = Mn;

        // LDS visibility only; emission prefetch stays in flight (no vmcnt drain)
        asm volatile("s_waitcnt lgkmcnt(0)" ::: "memory");
        __builtin_amdgcn_s_barrier();
        __builtin_amdgcn_sched_barrier(0);
    };

#define IC(v) std::integral_constant<int, v>{}
#define BC(v) std::integral_constant<bool, v>{}
    step(0, IC(0), BC(true));
    step(1, IC(1), BC(true));
    step(2, IC(2), BC(true));
    step(3, IC(3), BC(true));
    for (int jj = 4; jj < CS; jj += 4) {
        step(jj + 0, IC(0), BC(false));
        step(jj + 1, IC(1), BC(false));
        step(jj + 2, IC(2), BC(false));
        step(jj + 3, IC(3), BC(false));
    }
#undef IC
#undef BC

    // ls[128] = M_127 + log(sum_k e_127)
    float s = e_last;
#pragma unroll
    for (int o = 32; o; o >>= 1) s += __shfl_xor(s, o, 64);
    if (lane == 0) red[wv] = s;
    __syncthreads();
    if (tid == 0) {
        float tot = red[0] + red[1] + red[2] + red[3];
        float ls_full = M_last + __logf(tot);
        if (len == CS) out_r = ls_full;
        out[b] = out_r;
    }
}

extern "C" void kernel_launch(void* const* d_in, const int* in_sizes, int n_in,
                              void* d_out, int out_size, void* d_ws, size_t ws_size,
                              hipStream_t stream) {
    const float* logits    = (const float*)d_in[0];
    const float* T         = (const float*)d_in[1];
    const float* ham       = (const float*)d_in[2];
    const float* tag_mask  = (const float*)d_in[3];
    const int*   text_mask = (const int*)d_in[4];
    float* out = (float*)d_out;

    // prep_eT fused into the scan kernel's init (d_ws unused)
    crf_scan_kernel<<<CB, 256, 0, stream>>>(logits, T, ham, tag_mask, text_mask, out);
}

// Round 12
// 176.719 us; speedup vs baseline: 1.1779x; 1.0361x over previous
//
#include <hip/hip_runtime.h>
#include <hip/hip_bf16.h>
#include <type_traits>

typedef __attribute__((ext_vector_type(8))) _Float16 half8;
typedef __attribute__((ext_vector_type(4))) _Float16 half4;
typedef __attribute__((ext_vector_type(4))) float f32x4;

constexpr int CB = 48, CS = 128, CW = 4, CK = 256;
constexpr int LDP = 264;  // padded ebuf row stride (halves)

// eT[b][k][kp] = exp(T[b][k][kp] * tag_mask[b][k][kp]) as f16, float4-vectorized.
// Separate full-GPU-width kernel (6144 blocks): streams 25MB in / 6.3MB out at full BW.
// Fusing this into the scan (round 11) put the reads on the 48-block serial path: +17us.
__global__ void prep_eT_kernel(const f32x4* __restrict__ T,
                               const f32x4* __restrict__ tm,
                               half4* __restrict__ eT, int n4) {
    int i = blockIdx.x * 256 + threadIdx.x;
    if (i < n4) {
        f32x4 t = T[i], m = tm[i];
        half4 o;
        o[0] = (_Float16)__expf(t[0] * m[0]);
        o[1] = (_Float16)__expf(t[1] * m[1]);
        o[2] = (_Float16)__expf(t[2] * m[2]);
        o[3] = (_Float16)__expf(t[3] * m[3]);
        eT[i] = o;
    }
}

// 4 waves / 256 threads, 1 wave/SIMD (full register budget — every >=2 waves/SIMD
// variant spilled at the hipcc 128-VGPR cap). Measured-best structure (round 5):
// - persistent eT B-fragments in AGPR/VGPR, persistent slot-duplicated A-fragments
//   with masked single-row LDS reload (conflict-free broadcast)
// - all-ones MFMA tile for rowsums (no cross-lane chain)
// - deferred normalizer: scl for step j predicted at step j-1 (log/exp off store path)
// - 4-deep emission prefetch; raw s_barrier + lgkmcnt-only wait (loads stay in flight)
// Ledger (12 rounds): head-of-step VALU/cross-lane grafts, chain splits, Y-memo,
// 8-wave/dual-batch, and prep fusion all measured worse. The 84us scan is
// recurrence-latency bound: 128 serial steps x ~1583cy (~776 MFMA issue + chain).
__global__ __launch_bounds__(256, 1)
void crf_scan_kernel(const float* __restrict__ logits,
                     const float* __restrict__ ham,
                     const _Float16* __restrict__ eT,
                     const float* __restrict__ tag_mask,
                     const int* __restrict__ text_mask,
                     float* __restrict__ out) {
    const int b = blockIdx.x;
    const int tid = (int)threadIdx.x;
    const int wv = tid >> 6;
    const int lane = tid & 63;
    const int l16 = lane & 15;
    const int g4 = lane >> 4;

    __shared__ alignas(16) _Float16 ebuf[4 * LDP];  // ring: slot of alpha_i = i&3
    __shared__ float red[4];
    __shared__ int len_s;

    if (tid == 0) len_s = 0;
    __syncthreads();
    if (tid < CS) atomicAdd(&len_s, text_mask[b * CS + tid]);
    // alpha_{-1} = zeros row: e = exp(0-0) = 1 in slot 3, M_{-1} = 0
    ebuf[3 * LDP + tid] = (_Float16)1.0f;

    const float tm0 = tag_mask[(size_t)b * CK * CK + tid];  // tag_mask[b,0,k]

    // persistent eT B-fragments (AGPR/VGPR-resident for all 128 steps)
    half8 bfr[8][4];
    const _Float16* eTb = eT + (size_t)b * CK * CK;
#pragma unroll
    for (int c = 0; c < 8; ++c)
#pragma unroll
        for (int t = 0; t < 4; ++t) {
            int k = wv * 64 + t * 16 + l16;
            bfr[c][t] = *(const half8*)(eTb + (size_t)k * CK + c * 32 + g4 * 8);
        }

    const float* lgb = logits + (size_t)b * CS * CW * CK;
    const float* hcb = ham    + (size_t)b * CS * CW * CK;

    // persistent A-fragments, slot-duplicated rows: A row r holds slot (r&3).
    half8 af[8];
    {
        const _Float16 iv = ((l16 & 3) == 3) ? (_Float16)1.0f : (_Float16)0.0f;
        half8 v;
#pragma unroll
        for (int i = 0; i < 8; ++i) v[i] = iv;
#pragma unroll
        for (int c = 0; c < 8; ++c) af[c] = v;
    }

    // wave-uniform scan state
    float mr[4] = {0.0f, 0.0f, 0.0f, 0.0f};  // mr[s] = normalizer M of alpha in slot s
    float ls_prev = __logf(256.0f) - 2.0f;   // pretend ls_{-1}
    float out_r = __logf(256.0f);            // ls[0] (len==0 case)
    float e_last = 0.0f, M_last = 0.0f;
    // deferred normalizer: Mcur/scl for step j are decided at step j-1.
    float Mcur = __logf(256.0f) + 2.0f;      // M_0 = log256 + 2
    float scl  = __expf(0.0f - Mcur);        // C_0 = mr[3] = 0

    // 4-deep emission prefetch: set s holds step with j&3==s
    float lgp[4][4], hcp[4][4];
#pragma unroll
    for (int s = 0; s < 4; ++s)
#pragma unroll
        for (int w = 0; w < 4; ++w) {
            int idx = s * (CW * CK) + w * CK + tid;
            lgp[s][w] = lgb[idx];
            hcp[s][w] = hcb[idx];
        }

    __syncthreads();
    const int len = len_s;

    half8 ones;
#pragma unroll
    for (int i = 0; i < 8; ++i) ones[i] = (_Float16)1.0f;

    auto step = [&](int j, auto uc, auto firstc) {
        constexpr int u = uc.value;          // j & 3 (slot written this step)
        constexpr bool first = firstc.value; // j < 4 block
        constexpr int sp = (u + 3) & 3;      // slot of alpha_{j-1}

        // masked A-frag update: only row group sp changed since last step (16/64 lanes,
        // broadcast addresses within each group -> conflict-free)
        if ((l16 & 3) == sp) {
#pragma unroll
            for (int c = 0; c < 8; ++c)
                af[c] = *(const half8*)(ebuf + sp * LDP + c * 32 + g4 * 8);
        }

        // consume prefetch set u (issued 4 steps ago)
        float em_w[4];
#pragma unroll
        for (int w = 0; w < 4; ++w)
            em_w[w] = (lgp[u][w] + hcp[u][w]) * tm0;

        // reissue set u for step j+4 (stays in flight across raw barriers)
        {
            int jn = (j + 4 < CS) ? j + 4 : 0;  // wave-uniform clamp (dummy ok)
#pragma unroll
            for (int w = 0; w < 4; ++w) {
                int idx = jn * (CW * CK) + w * CK + tid;
                lgp[u][w] = lgb[idx];
                hcp[u][w] = hcb[idx];
            }
        }

        // slot weights need only mr[]/C (known since last step) -> off the MFMA path
        const float C = mr[sp];
        float E[4];
#pragma unroll
        for (int r = 0; r < 4; ++r)
            E[r] = __expf(mr[r] + em_w[(u + 3 - r) & 3] - C);
        mr[u] = Mcur;   // record this step's normalizer (after E read old mr[u])

        // MFMA: y[slot r][k] for 4 k-tiles + all-ones tile for row sums
        f32x4 acc[4];
#pragma unroll
        for (int t = 0; t < 4; ++t) acc[t] = (f32x4){0.0f, 0.0f, 0.0f, 0.0f};
        f32x4 s0 = {0, 0, 0, 0}, s1 = {0, 0, 0, 0};
#pragma unroll
        for (int c = 0; c < 8; ++c) {
#pragma unroll
            for (int t = 0; t < 4; ++t)
                acc[t] = __builtin_amdgcn_mfma_f32_16x16x32_f16(af[c], bfr[c][t], acc[t], 0, 0, 0);
            if (c & 1) s1 = __builtin_amdgcn_mfma_f32_16x16x32_f16(af[c], ones, s1, 0, 0, 0);
            else       s0 = __builtin_amdgcn_mfma_f32_16x16x32_f16(af[c], ones, s0, 0, 0, 0);
        }
        f32x4 rsum = s0 + s1;   // rsum[r] = rowsum of slot r (wave-uniform)

        // transpose-free epilogue: lane's k = tid lives in tile t = g4, reg r = slot r
        float S = 0.0f;
#pragma unroll
        for (int r = 0; r < 4; ++r) {
            float v01 = (g4 & 1) ? acc[1][r] : acc[0][r];
            float v23 = (g4 & 1) ? acc[3][r] : acc[2][r];
            float yv  = (g4 & 2) ? v23 : v01;
            if (first) {
                const int w = (u + 3 - r) & 3;   // width feeding slot r this step
                if (w == j) yv = 256.0f;         // initial-state path (alpha_{-1}=0 over K)
                else if (w > j) yv = 0.0f;       // invalid span
            }
            S = fmaf(yv, E[r], S);
        }
        float e = S * scl;                       // scl precomputed last step
        ebuf[u * LDP + tid] = (_Float16)e;
        e_last = e;
        M_last = Mcur;

        // trail (off the store path): ls_j, output select, next normalizer
        float lsj = C + __logf(rsum[sp]);        // ls[j] = LSE(alpha_{j-1})
        if (j == len) out_r = lsj;
        float delta = lsj - ls_prev;
        ls_prev = lsj;
        float Mn = lsj + 2.0f * delta;           // predict ls_{j+1} + delta_{j+1}
        scl = __expf(Mcur - Mn);                 // C_{j+1} = M_j = Mcur
        Mcur = Mn;

        // LDS visibility only; emission prefetch stays in flight (no vmcnt drain)
        asm volatile("s_waitcnt lgkmcnt(0)" ::: "memory");
        __builtin_amdgcn_s_barrier();
        __builtin_amdgcn_sched_barrier(0);
    };

#define IC(v) std::integral_constant<int, v>{}
#define BC(v) std::integral_constant<bool, v>{}
    step(0, IC(0), BC(true));
    step(1, IC(1), BC(true));
    step(2, IC(2), BC(true));
    step(3, IC(3), BC(true));
    for (int jj = 4; jj < CS; jj += 4) {
        step(jj + 0, IC(0), BC(false));
        step(jj + 1, IC(1), BC(false));
        step(jj + 2, IC(2), BC(false));
        step(jj + 3, IC(3), BC(false));
    }
#undef IC
#undef BC

    // ls[128] = M_127 + log(sum_k e_127)
    float s = e_last;
#pragma unroll
    for (int o = 32; o; o >>= 1) s += __shfl_xor(s, o, 64);
    if (lane == 0) red[wv] = s;
    __syncthreads();
    if (tid == 0) {
        float tot = red[0] + red[1] + red[2] + red[3];
        float ls_full = M_last + __logf(tot);
        if (len == CS) out_r = ls_full;
        out[b] = out_r;
    }
}

extern "C" void kernel_launch(void* const* d_in, const int* in_sizes, int n_in,
                              void* d_out, int out_size, void* d_ws, size_t ws_size,
                              hipStream_t stream) {
    const float* logits    = (const float*)d_in[0];
    const float* T         = (const float*)d_in[1];
    const float* ham       = (const float*)d_in[2];
    const float* tag_mask  = (const float*)d_in[3];
    const int*   text_mask = (const int*)d_in[4];
    float* out = (float*)d_out;

    _Float16* eT = (_Float16*)d_ws;  // CB*CK*CK f16 = 6.3 MB scratch
    int n4 = CB * CK * CK / 4;
    prep_eT_kernel<<<(n4 + 255) / 256, 256, 0, stream>>>(
        (const f32x4*)T, (const f32x4*)tag_mask, (half4*)eT, n4);
    crf_scan_kernel<<<CB, 256, 0, stream>>>(logits, ham, eT, tag_mask, text_mask, out);
}